// Round 1
// baseline (361.055 us; speedup 1.0000x reference)
//
#include <hip/hip_runtime.h>

#define BN_EPS 1e-5f

// ws layout (floats):
//   stats[0..28)   sum1      [28..56) ssq1
//   stats[56..64)  sum2      [64..72) ssq2
//   stats[72..100) scale1    [100..128) shift1
//   stats[128..136) scale2   [136..144) shift2
//   P  at ws+256            (N*56)
//   y1 at P + N*56          (E*28)
//   y2 at y1 + E*28         (E*8)

// K1: per-node projection P[n][0..27] = h[n]@W1a.T, P[n][28..55] = h[n]@W1b.T.
// Also zeroes the stats accumulators (ws is re-poisoned before every launch).
__global__ void k1_proj(const float* __restrict__ h, const float* __restrict__ W1,
                        float* __restrict__ P, float* __restrict__ stats, int N) {
  if (blockIdx.x == 0 && threadIdx.x < 72) stats[threadIdx.x] = 0.f;
  const int total = N * 56;
  const int stride = gridDim.x * blockDim.x;
  for (int idx = blockIdx.x * blockDim.x + threadIdx.x; idx < total; idx += stride) {
    const int n = idx / 56;
    const int c = idx - n * 56;
    // W1 row stride 268; byte offsets are 16B-aligned (268*4=1072=67*16, 128*4=512)
    const float* wp = (c < 28) ? (W1 + c * 268) : (W1 + (c - 28) * 268 + 128);
    const float4* w4 = (const float4*)wp;
    const float4* h4 = (const float4*)(h + n * 128);
    float acc = 0.f;
#pragma unroll 8
    for (int k = 0; k < 32; k++) {
      float4 a = h4[k], b = w4[k];
      acc += a.x * b.x + a.y * b.y + a.z * b.z + a.w * b.w;
    }
    P[idx] = acc;  // idx == n*56 + c
  }
}

// K2: per-edge layer 1: y1[e][c] = P[src][c] + P[dst][28+c] + ef[e]@W1c[c] + b1[c]
// lanes: c = tid&31 (active c<28), 2 edges per wave. Accumulates per-channel
// sum/ssq, block-reduces, one atomicAdd per channel per block.
__global__ void k2_edge(const float* __restrict__ P, const float* __restrict__ ef,
                        const int* __restrict__ src, const int* __restrict__ dst,
                        const float* __restrict__ W1, const float* __restrict__ b1,
                        float* __restrict__ y1, float* __restrict__ stats, int E) {
  const int tid = threadIdx.x;
  const int c = tid & 31;
  const int g = tid >> 5;
  const bool act = (c < 28);
  float w[12];
  float bias = 0.f;
  if (act) {
    const float4* wp = (const float4*)(W1 + c * 268 + 256);  // 16B aligned
    float4 w0 = wp[0], w1 = wp[1], w2 = wp[2];
    w[0] = w0.x; w[1] = w0.y; w[2] = w0.z; w[3] = w0.w;
    w[4] = w1.x; w[5] = w1.y; w[6] = w1.z; w[7] = w1.w;
    w[8] = w2.x; w[9] = w2.y; w[10] = w2.z; w[11] = w2.w;
    bias = b1[c];
  }
  float sum = 0.f, ssq = 0.f;
  const int gstride = gridDim.x * 8;
  for (int e = blockIdx.x * 8 + g; e < E; e += gstride) {
    const int s = src[e], d = dst[e];
    if (act) {
      const float pa = P[s * 56 + c];
      const float pb = P[d * 56 + 28 + c];
      const float4* e4 = (const float4*)(ef + e * 12);  // e*48B, 16B aligned
      float4 f0 = e4[0], f1 = e4[1], f2 = e4[2];
      float acc = bias
          + f0.x * w[0] + f0.y * w[1] + f0.z * w[2] + f0.w * w[3]
          + f1.x * w[4] + f1.y * w[5] + f1.z * w[6] + f1.w * w[7]
          + f2.x * w[8] + f2.y * w[9] + f2.z * w[10] + f2.w * w[11];
      const float v = acc + pa + pb;
      y1[e * 28 + c] = v;
      sum += v;
      ssq += v * v;
    }
  }
  // pair lanes (g even/odd within wave) share channel c
  sum += __shfl_xor(sum, 32);
  ssq += __shfl_xor(ssq, 32);
  __shared__ float red[2][4][28];
  const int wave = tid >> 6, lane = tid & 63;
  if (lane < 28) { red[0][wave][lane] = sum; red[1][wave][lane] = ssq; }
  __syncthreads();
  if (tid < 28) {
    atomicAdd(&stats[tid], red[0][0][tid] + red[0][1][tid] + red[0][2][tid] + red[0][3][tid]);
    atomicAdd(&stats[28 + tid], red[1][0][tid] + red[1][1][tid] + red[1][2][tid] + red[1][3][tid]);
  }
}

// K3: finalize BN1 -> scale1/shift1
__global__ void k3_fin1(const float* __restrict__ gamma, const float* __restrict__ beta,
                        float* __restrict__ stats, float invE) {
  const int c = threadIdx.x;
  if (c < 28) {
    const float mean = stats[c] * invE;
    const float var = stats[28 + c] * invE - mean * mean;
    const float sc = gamma[c] * rsqrtf(var + BN_EPS);
    stats[72 + c] = sc;
    stats[100 + c] = beta[c] - mean * sc;
  }
}

// K4: s1 = relu(BN1(y1)); y2 = s1@W2.T + b2; accumulate stats2.
__global__ void k4_l2(const float* __restrict__ y1, const float* __restrict__ stats,
                      const float* __restrict__ W2, const float* __restrict__ b2,
                      float* __restrict__ y2, float* __restrict__ stats2, int E) {
  float as[8], aq[8];
#pragma unroll
  for (int o = 0; o < 8; o++) { as[o] = 0.f; aq[o] = 0.f; }
  const int stride = gridDim.x * blockDim.x;
  for (int e = blockIdx.x * blockDim.x + threadIdx.x; e < E; e += stride) {
    const float4* p = (const float4*)(y1 + e * 28);  // 112B, 16B aligned
    float s1[28];
#pragma unroll
    for (int q = 0; q < 7; q++) {
      float4 v = p[q];
      s1[q * 4 + 0] = v.x; s1[q * 4 + 1] = v.y; s1[q * 4 + 2] = v.z; s1[q * 4 + 3] = v.w;
    }
    float acc[8];
#pragma unroll
    for (int o = 0; o < 8; o++) acc[o] = b2[o];
#pragma unroll
    for (int cc = 0; cc < 28; cc++) {
      float s = fmaxf(s1[cc] * stats[72 + cc] + stats[100 + cc], 0.f);
#pragma unroll
      for (int o = 0; o < 8; o++) acc[o] += W2[o * 28 + cc] * s;  // uniform -> s_load
    }
    float4* yo = (float4*)(y2 + e * 8);
    yo[0] = make_float4(acc[0], acc[1], acc[2], acc[3]);
    yo[1] = make_float4(acc[4], acc[5], acc[6], acc[7]);
#pragma unroll
    for (int o = 0; o < 8; o++) { as[o] += acc[o]; aq[o] += acc[o] * acc[o]; }
  }
  // wave reduce 16 scalars, then block reduce via LDS, 16 atomics per block
#pragma unroll
  for (int o = 0; o < 8; o++) {
    for (int off = 32; off; off >>= 1) {
      as[o] += __shfl_down(as[o], off);
      aq[o] += __shfl_down(aq[o], off);
    }
  }
  __shared__ float redS[4][16];
  const int wave = threadIdx.x >> 6, lane = threadIdx.x & 63;
  if (lane == 0) {
#pragma unroll
    for (int o = 0; o < 8; o++) { redS[wave][o] = as[o]; redS[wave][8 + o] = aq[o]; }
  }
  __syncthreads();
  if (threadIdx.x < 16) {
    const int t = threadIdx.x;
    atomicAdd(&stats2[t], redS[0][t] + redS[1][t] + redS[2][t] + redS[3][t]);
  }
}

// K5: finalize BN2 -> scale2/shift2
__global__ void k5_fin2(const float* __restrict__ gamma, const float* __restrict__ beta,
                        float* __restrict__ stats, float invE) {
  const int c = threadIdx.x;
  if (c < 8) {
    const float mean = stats[56 + c] * invE;
    const float var = stats[64 + c] * invE - mean * mean;
    const float sc = gamma[c] * rsqrtf(var + BN_EPS);
    stats[128 + c] = sc;
    stats[136 + c] = beta[c] - mean * sc;
  }
}

// K6: out = relu(BN2(y2)) @ W3.T + b3
__global__ void k6_l3(const float* __restrict__ y2, const float* __restrict__ stats,
                      const float* __restrict__ W3, const float* __restrict__ b3,
                      float* __restrict__ out, int E) {
  const int e = blockIdx.x * blockDim.x + threadIdx.x;
  if (e >= E) return;
  const float4* p = (const float4*)(y2 + e * 8);
  float4 a = p[0], b4 = p[1];
  float v[8] = {a.x, a.y, a.z, a.w, b4.x, b4.y, b4.z, b4.w};
  float acc = b3[0];
#pragma unroll
  for (int o = 0; o < 8; o++) {
    float s = fmaxf(v[o] * stats[128 + o] + stats[136 + o], 0.f);
    acc += W3[o] * s;
  }
  out[e] = acc;
}

extern "C" void kernel_launch(void* const* d_in, const int* in_sizes, int n_in,
                              void* d_out, int out_size, void* d_ws, size_t ws_size,
                              hipStream_t stream) {
  const float* h   = (const float*)d_in[0];
  const float* ef  = (const float*)d_in[1];
  const int* src   = (const int*)d_in[2];
  const int* dst   = (const int*)d_in[3];
  const float* W1  = (const float*)d_in[4];
  const float* b1  = (const float*)d_in[5];
  const float* g1  = (const float*)d_in[6];
  const float* be1 = (const float*)d_in[7];
  const float* W2  = (const float*)d_in[8];
  const float* b2  = (const float*)d_in[9];
  const float* g2  = (const float*)d_in[10];
  const float* be2 = (const float*)d_in[11];
  const float* W3  = (const float*)d_in[12];
  const float* b3  = (const float*)d_in[13];
  float* out = (float*)d_out;

  const int N = in_sizes[0] / 128;
  const int E = in_sizes[2];
  const float invE = 1.0f / (float)E;

  float* ws = (float*)d_ws;
  float* stats = ws;                 // 144 floats used
  float* P  = ws + 256;              // N*56
  float* y1 = P + (size_t)N * 56;    // E*28
  float* y2 = y1 + (size_t)E * 28;   // E*8

  k1_proj<<<512, 256, 0, stream>>>(h, W1, P, stats, N);
  k2_edge<<<1280, 256, 0, stream>>>(P, ef, src, dst, W1, b1, y1, stats, E);
  k3_fin1<<<1, 32, 0, stream>>>(g1, be1, stats, invE);
  k4_l2<<<1172, 256, 0, stream>>>(y1, stats, W2, b2, y2, stats + 56, E);
  k5_fin2<<<1, 64, 0, stream>>>(g2, be2, stats, invE);
  k6_l3<<<(E + 255) / 256, 256, 0, stream>>>(y2, stats, W3, b3, out, E);
}

// Round 2
// 286.596 us; speedup vs baseline: 1.2598x; 1.2598x over previous
//
#include <hip/hip_runtime.h>

#define BN_EPS 1e-5f

// ws layout (floats):
//   stats[0..28)   sum1      [28..56) ssq1
//   stats[56..64)  sum2      [64..72) ssq2
//   stats[72..100) scale1    [100..128) shift1
//   stats[128..136) scale2   [136..144) shift2
//   P  at ws+256            (N*56)
//   y1 at P + N*56          (E*28)
//   y2 at y1 + E*28         (E*8)

// K1 v2: thread-per-node, 28 channels per thread, two blocks per 256-node
// range (blockIdx&1 selects channel half). W addresses are wave-uniform
// (block/loop indices only) -> scalar loads feeding v_fmac; h rows are
// per-lane float4 loads, each cache line consumed exactly once.
__global__ void k1_proj(const float* __restrict__ h, const float* __restrict__ W1,
                        float* __restrict__ P, float* __restrict__ stats, int N) {
  if (blockIdx.x == 0 && threadIdx.x < 72) stats[threadIdx.x] = 0.f;
  const int half = blockIdx.x & 1;            // 0: channels 0..27, 1: 28..55
  const int node = (blockIdx.x >> 1) * 256 + threadIdx.x;
  if (node >= N) return;

  // channel c (local 0..27) maps to W1 row (half*0 + c) ... W1[c][half*128 + k]
  // i.e. global output channel = half*28 + c, reading k-range [half*128, half*128+128)
  const float* __restrict__ wbase = W1 + half * 128;  // + c*268 + k
  const float4* __restrict__ h4 = (const float4*)(h + (size_t)node * 128);

  float acc[28];
#pragma unroll
  for (int c = 0; c < 28; c++) acc[c] = 0.f;

  // k in chunks of 8 (two float4 of h); W reads are uniform -> s_load
  for (int kk = 0; kk < 16; kk++) {
    const float4 a = h4[kk * 2];
    const float4 b = h4[kk * 2 + 1];
#pragma unroll
    for (int c = 0; c < 28; c++) {
      const float* w = wbase + c * 268 + kk * 8;  // uniform address
      acc[c] += a.x * w[0] + a.y * w[1] + a.z * w[2] + a.w * w[3]
              + b.x * w[4] + b.y * w[5] + b.z * w[6] + b.w * w[7];
    }
  }

  // write 28 consecutive floats: P[node*56 + half*28 .. +28), 16B aligned
  float4* po = (float4*)(P + (size_t)node * 56 + half * 28);
#pragma unroll
  for (int q = 0; q < 7; q++) {
    po[q] = make_float4(acc[q * 4], acc[q * 4 + 1], acc[q * 4 + 2], acc[q * 4 + 3]);
  }
}

// K2: per-edge layer 1: y1[e][c] = P[src][c] + P[dst][28+c] + ef[e]@W1c[c] + b1[c]
__global__ void k2_edge(const float* __restrict__ P, const float* __restrict__ ef,
                        const int* __restrict__ src, const int* __restrict__ dst,
                        const float* __restrict__ W1, const float* __restrict__ b1,
                        float* __restrict__ y1, float* __restrict__ stats, int E) {
  const int tid = threadIdx.x;
  const int c = tid & 31;
  const int g = tid >> 5;
  const bool act = (c < 28);
  float w[12];
  float bias = 0.f;
  if (act) {
    const float4* wp = (const float4*)(W1 + c * 268 + 256);  // 16B aligned
    float4 w0 = wp[0], w1 = wp[1], w2 = wp[2];
    w[0] = w0.x; w[1] = w0.y; w[2] = w0.z; w[3] = w0.w;
    w[4] = w1.x; w[5] = w1.y; w[6] = w1.z; w[7] = w1.w;
    w[8] = w2.x; w[9] = w2.y; w[10] = w2.z; w[11] = w2.w;
    bias = b1[c];
  }
  float sum = 0.f, ssq = 0.f;
  const int gstride = gridDim.x * 8;
  for (int e = blockIdx.x * 8 + g; e < E; e += gstride) {
    const int s = src[e], d = dst[e];
    if (act) {
      const float pa = P[s * 56 + c];
      const float pb = P[d * 56 + 28 + c];
      const float4* e4 = (const float4*)(ef + e * 12);  // e*48B, 16B aligned
      float4 f0 = e4[0], f1 = e4[1], f2 = e4[2];
      float acc = bias
          + f0.x * w[0] + f0.y * w[1] + f0.z * w[2] + f0.w * w[3]
          + f1.x * w[4] + f1.y * w[5] + f1.z * w[6] + f1.w * w[7]
          + f2.x * w[8] + f2.y * w[9] + f2.z * w[10] + f2.w * w[11];
      const float v = acc + pa + pb;
      y1[e * 28 + c] = v;
      sum += v;
      ssq += v * v;
    }
  }
  // pair lanes (g even/odd within wave) share channel c
  sum += __shfl_xor(sum, 32);
  ssq += __shfl_xor(ssq, 32);
  __shared__ float red[2][4][28];
  const int wave = tid >> 6, lane = tid & 63;
  if (lane < 28) { red[0][wave][lane] = sum; red[1][wave][lane] = ssq; }
  __syncthreads();
  if (tid < 28) {
    atomicAdd(&stats[tid], red[0][0][tid] + red[0][1][tid] + red[0][2][tid] + red[0][3][tid]);
    atomicAdd(&stats[28 + tid], red[1][0][tid] + red[1][1][tid] + red[1][2][tid] + red[1][3][tid]);
  }
}

// K3: finalize BN1 -> scale1/shift1
__global__ void k3_fin1(const float* __restrict__ gamma, const float* __restrict__ beta,
                        float* __restrict__ stats, float invE) {
  const int c = threadIdx.x;
  if (c < 28) {
    const float mean = stats[c] * invE;
    const float var = stats[28 + c] * invE - mean * mean;
    const float sc = gamma[c] * rsqrtf(var + BN_EPS);
    stats[72 + c] = sc;
    stats[100 + c] = beta[c] - mean * sc;
  }
}

// K4: s1 = relu(BN1(y1)); y2 = s1@W2.T + b2; accumulate stats2.
__global__ void k4_l2(const float* __restrict__ y1, const float* __restrict__ stats,
                      const float* __restrict__ W2, const float* __restrict__ b2,
                      float* __restrict__ y2, float* __restrict__ stats2, int E) {
  float as[8], aq[8];
#pragma unroll
  for (int o = 0; o < 8; o++) { as[o] = 0.f; aq[o] = 0.f; }
  const int stride = gridDim.x * blockDim.x;
  for (int e = blockIdx.x * blockDim.x + threadIdx.x; e < E; e += stride) {
    const float4* p = (const float4*)(y1 + e * 28);  // 112B, 16B aligned
    float s1[28];
#pragma unroll
    for (int q = 0; q < 7; q++) {
      float4 v = p[q];
      s1[q * 4 + 0] = v.x; s1[q * 4 + 1] = v.y; s1[q * 4 + 2] = v.z; s1[q * 4 + 3] = v.w;
    }
    float acc[8];
#pragma unroll
    for (int o = 0; o < 8; o++) acc[o] = b2[o];
#pragma unroll
    for (int cc = 0; cc < 28; cc++) {
      float s = fmaxf(s1[cc] * stats[72 + cc] + stats[100 + cc], 0.f);
#pragma unroll
      for (int o = 0; o < 8; o++) acc[o] += W2[o * 28 + cc] * s;  // uniform -> s_load
    }
    float4* yo = (float4*)(y2 + e * 8);
    yo[0] = make_float4(acc[0], acc[1], acc[2], acc[3]);
    yo[1] = make_float4(acc[4], acc[5], acc[6], acc[7]);
#pragma unroll
    for (int o = 0; o < 8; o++) { as[o] += acc[o]; aq[o] += acc[o] * acc[o]; }
  }
  // wave reduce 16 scalars, then block reduce via LDS, 16 atomics per block
#pragma unroll
  for (int o = 0; o < 8; o++) {
    for (int off = 32; off; off >>= 1) {
      as[o] += __shfl_down(as[o], off);
      aq[o] += __shfl_down(aq[o], off);
    }
  }
  __shared__ float redS[4][16];
  const int wave = threadIdx.x >> 6, lane = threadIdx.x & 63;
  if (lane == 0) {
#pragma unroll
    for (int o = 0; o < 8; o++) { redS[wave][o] = as[o]; redS[wave][8 + o] = aq[o]; }
  }
  __syncthreads();
  if (threadIdx.x < 16) {
    const int t = threadIdx.x;
    atomicAdd(&stats2[t], redS[0][t] + redS[1][t] + redS[2][t] + redS[3][t]);
  }
}

// K5: finalize BN2 -> scale2/shift2
__global__ void k5_fin2(const float* __restrict__ gamma, const float* __restrict__ beta,
                        float* __restrict__ stats, float invE) {
  const int c = threadIdx.x;
  if (c < 8) {
    const float mean = stats[56 + c] * invE;
    const float var = stats[64 + c] * invE - mean * mean;
    const float sc = gamma[c] * rsqrtf(var + BN_EPS);
    stats[128 + c] = sc;
    stats[136 + c] = beta[c] - mean * sc;
  }
}

// K6: out = relu(BN2(y2)) @ W3.T + b3
__global__ void k6_l3(const float* __restrict__ y2, const float* __restrict__ stats,
                      const float* __restrict__ W3, const float* __restrict__ b3,
                      float* __restrict__ out, int E) {
  const int e = blockIdx.x * blockDim.x + threadIdx.x;
  if (e >= E) return;
  const float4* p = (const float4*)(y2 + e * 8);
  float4 a = p[0], b4 = p[1];
  float v[8] = {a.x, a.y, a.z, a.w, b4.x, b4.y, b4.z, b4.w};
  float acc = b3[0];
#pragma unroll
  for (int o = 0; o < 8; o++) {
    float s = fmaxf(v[o] * stats[128 + o] + stats[136 + o], 0.f);
    acc += W3[o] * s;
  }
  out[e] = acc;
}

extern "C" void kernel_launch(void* const* d_in, const int* in_sizes, int n_in,
                              void* d_out, int out_size, void* d_ws, size_t ws_size,
                              hipStream_t stream) {
  const float* h   = (const float*)d_in[0];
  const float* ef  = (const float*)d_in[1];
  const int* src   = (const int*)d_in[2];
  const int* dst   = (const int*)d_in[3];
  const float* W1  = (const float*)d_in[4];
  const float* b1  = (const float*)d_in[5];
  const float* g1  = (const float*)d_in[6];
  const float* be1 = (const float*)d_in[7];
  const float* W2  = (const float*)d_in[8];
  const float* b2  = (const float*)d_in[9];
  const float* g2  = (const float*)d_in[10];
  const float* be2 = (const float*)d_in[11];
  const float* W3  = (const float*)d_in[12];
  const float* b3  = (const float*)d_in[13];
  float* out = (float*)d_out;

  const int N = in_sizes[0] / 128;
  const int E = in_sizes[2];
  const float invE = 1.0f / (float)E;

  float* ws = (float*)d_ws;
  float* stats = ws;                 // 144 floats used
  float* P  = ws + 256;              // N*56
  float* y1 = P + (size_t)N * 56;    // E*28
  float* y2 = y1 + (size_t)E * 28;   // E*8

  const int nodeBlocks = (N + 255) / 256;
  k1_proj<<<nodeBlocks * 2, 256, 0, stream>>>(h, W1, P, stats, N);
  k2_edge<<<1280, 256, 0, stream>>>(P, ef, src, dst, W1, b1, y1, stats, E);
  k3_fin1<<<1, 32, 0, stream>>>(g1, be1, stats, invE);
  k4_l2<<<1172, 256, 0, stream>>>(y1, stats, W2, b2, y2, stats + 56, E);
  k5_fin2<<<1, 64, 0, stream>>>(g2, be2, stats, invE);
  k6_l3<<<(E + 255) / 256, 256, 0, stream>>>(y2, stats, W3, b3, out, E);
}